// Round 3
// baseline (222.800 us; speedup 1.0000x reference)
//
#include <hip/hip_runtime.h>

typedef __bf16 bf16x8 __attribute__((ext_vector_type(8)));
typedef float f32x4 __attribute__((ext_vector_type(4)));

#define BS 2
#define SEQ 2048
#define DM 1024
#define NH 16
#define DKH 64
#define GM 4096
#define GN 1024
#define GK 1024
#define NEGV (-1e9f)

// ws layout (ushort units). At overlaps Xq (Xq dead after projections).
#define OFF_XQ 0u
#define OFF_XK 4194304u
#define OFF_XV 8388608u
#define OFF_WQ 12582912u
#define OFF_WK 13631488u
#define OFF_WV 14680064u
#define OFF_WO 15728640u
#define OFF_QH 16777216u
#define OFF_KH 20971520u
#define OFF_VH 25165824u
#define OFF_AT 0u

#if __has_builtin(__builtin_amdgcn_exp2f)
#define EXP2(x) __builtin_amdgcn_exp2f(x)
#else
static __device__ __forceinline__ float EXP2(float x) {
    float r;
    asm volatile("v_exp_f32 %0, %1" : "=v"(r) : "v"(x));
    return r;
}
#endif

__device__ __forceinline__ unsigned cvt_pk(float lo, float hi) {
    unsigned r;
    asm volatile("v_cvt_pk_bf16_f32 %0, %1, %2" : "=v"(r) : "v"(lo), "v"(hi));
    return r;
}

__device__ __forceinline__ unsigned short f2b(float f) {
    unsigned u = __builtin_bit_cast(unsigned, f);
    u += 0x7fffu + ((u >> 16) & 1u);
    return (unsigned short)(u >> 16);
}

typedef const __attribute__((address_space(1))) unsigned int* gas_t;
typedef __attribute__((address_space(3))) unsigned int* las_t;

__device__ __forceinline__ void gload_lds16(const ushort* g, ushort* l) {
    __builtin_amdgcn_global_load_lds((gas_t)(const void*)g, (las_t)(void*)l, 16, 0, 0);
}

__global__ __launch_bounds__(256)
void cvt_kernel(const float* __restrict__ q, const float* __restrict__ k,
                const float* __restrict__ v, const float* __restrict__ wq,
                const float* __restrict__ wk, const float* __restrict__ wv,
                const float* __restrict__ wo, ushort* __restrict__ ws)
{
    const float* src; unsigned n; unsigned dst;
    switch (blockIdx.y) {
        case 0: src = q;  n = 4194304u; dst = OFF_XQ; break;
        case 1: src = k;  n = 4194304u; dst = OFF_XK; break;
        case 2: src = v;  n = 4194304u; dst = OFF_XV; break;
        case 3: src = wq; n = 1048576u; dst = OFF_WQ; break;
        case 4: src = wk; n = 1048576u; dst = OFF_WK; break;
        case 5: src = wv; n = 1048576u; dst = OFF_WV; break;
        default: src = wo; n = 1048576u; dst = OFF_WO; break;
    }
    unsigned i = (blockIdx.x * 256u + threadIdx.x) * 4u;
    if (i >= n) return;
    float4 f = *(const float4*)(src + i);
    ushort4 o;
    o.x = f2b(f.x); o.y = f2b(f.y); o.z = f2b(f.z); o.w = f2b(f.w);
    *(ushort4*)(ws + dst + i) = o;
}

// C = A @ B^T, A:[4096][1024] bf16, B:[1024][1024] bf16, both row-major.
// m97 structure: linear LDS, global_load_lds width-16.
// PROJ: z in {0,1,2} -> (Xq,Wq)->Qh etc, bf16 head-split out, z==0 scaled 0.125*log2e.
// !PROJ: fp32 [4096][1024] out.
template<bool PROJ>
__global__ __launch_bounds__(256)
void gemm_bt(const ushort* __restrict__ Abase, const ushort* __restrict__ Bbase,
             ushort* __restrict__ obf, float* __restrict__ of)
{
    __shared__ __align__(16) ushort lA[128 * 64];
    __shared__ __align__(16) ushort lB[128 * 64];

    const ushort* A = Abase;
    const ushort* Bw = Bbase;
    ushort* dst = obf;
    float scale = 1.0f;
    if (PROJ) {
        unsigned z = blockIdx.z;
        A  += (size_t)z * (GM * GK);
        Bw += (size_t)z * (GN * GK);
        dst += (size_t)z * (GM * GN);
        if (z == 0) scale = 0.125f * 1.44269504088896f;  // 1/sqrt(64) * log2(e)
    }

    const int tid = threadIdx.x;
    const int lane = tid & 63, wid = tid >> 6;
    const int wr = wid >> 1, wc = wid & 1;
    const int lr = lane & 15, lg = lane >> 4;
    const int m0 = blockIdx.y * 128, n0 = blockIdx.x * 128;
    const int srow = wid * 32 + (lane >> 3);   // + p*8
    const int scol = (lane & 7) * 8;

    f32x4 acc[4][4] = {};

    for (int k0 = 0; k0 < GK; k0 += 64) {
        __syncthreads();
#pragma unroll
        for (int p = 0; p < 4; ++p) {
            gload_lds16(A + (size_t)(m0 + srow + p * 8) * GK + k0 + scol,
                        &lA[(wid * 32 + p * 8) * 64]);
            gload_lds16(Bw + (size_t)(n0 + srow + p * 8) * GK + k0 + scol,
                        &lB[(wid * 32 + p * 8) * 64]);
        }
        __syncthreads();
#pragma unroll
        for (int kk = 0; kk < 2; ++kk) {
            bf16x8 af[4], bfr[4];
#pragma unroll
            for (int i = 0; i < 4; ++i) {
                af[i]  = *(const bf16x8*)(&lA[(wr * 64 + i * 16 + lr) * 64 + kk * 32 + lg * 8]);
                bfr[i] = *(const bf16x8*)(&lB[(wc * 64 + i * 16 + lr) * 64 + kk * 32 + lg * 8]);
            }
#pragma unroll
            for (int i = 0; i < 4; ++i)
#pragma unroll
                for (int j = 0; j < 4; ++j)
                    acc[i][j] = __builtin_amdgcn_mfma_f32_16x16x32_bf16(af[i], bfr[j], acc[i][j], 0, 0, 0);
        }
    }

#pragma unroll
    for (int i = 0; i < 4; ++i) {
#pragma unroll
        for (int j = 0; j < 4; ++j) {
            int col = n0 + wc * 64 + j * 16 + lr;
#pragma unroll
            for (int r = 0; r < 4; ++r) {
                int row = m0 + wr * 64 + i * 16 + lg * 4 + r;
                float val = acc[i][j][r] * scale;
                if (PROJ) {
                    int b = row >> 11, s = row & 2047;
                    int hh = col >> 6, dk = col & 63;
                    dst[(((size_t)b * NH + hh) * SEQ + s) * DKH + dk] = f2b(val);
                } else {
                    of[(size_t)row * GN + col] = val;
                }
            }
        }
    }
}

// Flash attention, fixed-max (Q pre-scaled by 0.125*log2e; softmax = exp2 + sum).
// Block = (b, h, q-tile of 64). 4 waves x 16 q-rows. KV tile = 128.
// P layout sigma-permuted: lP[qrow][pos], pos = l*8 + fc holds key (pos&7)*16 + (pos>>3).
// lV[d][pos] holds V[key(pos)][d] (same sigma) so PV = sum over all keys.
__global__ __launch_bounds__(256)
void attn_kernel(ushort* __restrict__ ws, const int* __restrict__ mask)
{
    const int bid = blockIdx.x;
    const int qt = bid & 31;
    const int h  = (bid >> 5) & 15;
    const int b  = bid >> 9;

    const ushort* Qp = ws + OFF_QH + (size_t)(b * NH + h) * (SEQ * DKH);
    const ushort* Kp = ws + OFF_KH + (size_t)(b * NH + h) * (SEQ * DKH);
    const ushort* Vp = ws + OFF_VH + (size_t)(b * NH + h) * (SEQ * DKH);
    ushort* At = ws + OFF_AT;
    const int* mp = mask + (size_t)b * SEQ;

    __shared__ __align__(16) ushort lK[128][72];
    __shared__ __align__(16) ushort lV[64][136];
    __shared__ __align__(16) ushort lP[4][16][136];

    const int tid = threadIdx.x;
    const int lane = tid & 63, wid = tid >> 6;
    const int lr = lane & 15, lg = lane >> 4;
    ushort* lPw = &lP[wid][0][0];

    const int qrow0 = qt * 64 + wid * 16;
    bf16x8 qf[2];
#pragma unroll
    for (int kk = 0; kk < 2; ++kk)
        qf[kk] = *(const bf16x8*)(Qp + (size_t)(qrow0 + lr) * DKH + kk * 32 + lg * 8);

    f32x4 acc_o[4] = {};
    float lrun[4] = {0.f, 0.f, 0.f, 0.f};

    const int ksrow = tid >> 3, kscol = (tid & 7) * 8;   // K staging
    const int vd = tid & 63, vlb = tid >> 6;             // V staging

    for (int kt = 0; kt < SEQ / 128; ++kt) {
        const int kbase = kt * 128;
        __syncthreads();   // prev tile's lK/lV reads done
        // stage K tile [128][64] -> lK rows (padded 72)
#pragma unroll
        for (int p = 0; p < 4; ++p) {
            int r = p * 32 + ksrow;
            *(uint4*)(&lK[r][kscol]) =
                *(const uint4*)(Kp + (size_t)(kbase + r) * DKH + kscol);
        }
        // stage V^T sigma-permuted: lV[d][lblk*8+fc] = V[kbase + fc*16 + lblk][d]
#pragma unroll
        for (int i = 0; i < 4; ++i) {
            int lblk = i * 4 + vlb;
            ushort tmp[8];
#pragma unroll
            for (int fc = 0; fc < 8; ++fc)
                tmp[fc] = Vp[(size_t)(kbase + fc * 16 + lblk) * DKH + vd];
            *(uint4*)(&lV[vd][lblk * 8]) = *(const uint4*)tmp;
        }
        __syncthreads();

        // S = Q K^T (lane: q-row = lg*4+r, key = fc*16+lr)
        f32x4 s[8];
#pragma unroll
        for (int fc = 0; fc < 8; ++fc) {
            bf16x8 kf0 = *(const bf16x8*)(&lK[fc * 16 + lr][lg * 8]);
            bf16x8 kf1 = *(const bf16x8*)(&lK[fc * 16 + lr][32 + lg * 8]);
            f32x4 t = {};
            t = __builtin_amdgcn_mfma_f32_16x16x32_bf16(qf[0], kf0, t, 0, 0, 0);
            t = __builtin_amdgcn_mfma_f32_16x16x32_bf16(qf[1], kf1, t, 0, 0, 0);
            s[fc] = t;
        }

        int mv[8];
#pragma unroll
        for (int fc = 0; fc < 8; ++fc) mv[fc] = mp[kbase + fc * 16 + lr];

        // softmax (fixed max): p = 2^s, masked -> 0. Pack and store P row-wise.
#pragma unroll
        for (int r = 0; r < 4; ++r) {
            float p[8]; float ps = 0.f;
#pragma unroll
            for (int fc = 0; fc < 8; ++fc) {
                float sv = (mv[fc] == 0) ? NEGV : s[fc][r];
                p[fc] = EXP2(sv);
                ps += p[fc];
            }
            lrun[r] += ps;
            uint4 pk;
            pk.x = cvt_pk(p[0], p[1]);
            pk.y = cvt_pk(p[2], p[3]);
            pk.z = cvt_pk(p[4], p[5]);
            pk.w = cvt_pk(p[6], p[7]);
            *(uint4*)(lPw + (lg * 4 + r) * 136 + lr * 8) = pk;
        }

        // O += P @ V (sigma-consistent k-slots)
#pragma unroll
        for (int ks = 0; ks < 4; ++ks) {
            bf16x8 pf = *(const bf16x8*)(lPw + lr * 136 + ks * 32 + lg * 8);
#pragma unroll
            for (int fc2 = 0; fc2 < 4; ++fc2) {
                bf16x8 vf = *(const bf16x8*)(&lV[fc2 * 16 + lr][ks * 32 + lg * 8]);
                acc_o[fc2] = __builtin_amdgcn_mfma_f32_16x16x32_bf16(pf, vf, acc_o[fc2], 0, 0, 0);
            }
        }
    }

    // epilogue: reduce row-sums across lr (deferred), divide, write concat bf16
#pragma unroll
    for (int r = 0; r < 4; ++r) {
        float l = lrun[r];
        l += __shfl_xor(l, 1);
        l += __shfl_xor(l, 2);
        l += __shfl_xor(l, 4);
        l += __shfl_xor(l, 8);
        float rl = 1.0f / l;
        int qrow = qrow0 + lg * 4 + r;
#pragma unroll
        for (int fc2 = 0; fc2 < 4; ++fc2)
            At[((size_t)(b * SEQ) + qrow) * DM + h * DKH + fc2 * 16 + lr] =
                f2b(acc_o[fc2][r] * rl);
    }
}

extern "C" void kernel_launch(void* const* d_in, const int* in_sizes, int n_in,
                              void* d_out, int out_size, void* d_ws, size_t ws_size,
                              hipStream_t stream) {
    const float* kin = (const float*)d_in[0];
    const float* vin = (const float*)d_in[1];
    const float* qin = (const float*)d_in[2];
    const int*   msk = (const int*)d_in[3];
    const float* wq  = (const float*)d_in[4];
    const float* wk  = (const float*)d_in[5];
    const float* wv  = (const float*)d_in[6];
    const float* wo  = (const float*)d_in[7];
    ushort* ws = (ushort*)d_ws;
    float* out = (float*)d_out;

    cvt_kernel<<<dim3(4096, 7), 256, 0, stream>>>(qin, kin, vin, wq, wk, wv, wo, ws);
    gemm_bt<true><<<dim3(8, 32, 3), 256, 0, stream>>>(ws + OFF_XQ, ws + OFF_WQ, ws + OFF_QH, nullptr);
    attn_kernel<<<1024, 256, 0, stream>>>(ws, msk);
    gemm_bt<false><<<dim3(8, 32, 1), 256, 0, stream>>>(ws + OFF_AT, ws + OFF_WO, nullptr, out);
}

// Round 4
// 140.107 us; speedup vs baseline: 1.5902x; 1.5902x over previous
//
#include <hip/hip_runtime.h>

typedef __bf16 bf16x8 __attribute__((ext_vector_type(8)));
typedef float f32x4 __attribute__((ext_vector_type(4)));

#define BS 2
#define SEQ 2048
#define DM 1024
#define NH 16
#define DKH 64
#define GM 4096
#define GN 1024
#define GK 1024
#define NEGV (-1e9f)

// ws layout (ushort units). Timeline-safe aliasing:
//   Kc aliases Xq, VT aliases Xk (dead after projections).
//   At aliases Vh (dead after gather). idx/m live in Wq (dead after projections).
#define OFF_XQ 0u
#define OFF_XK 4194304u
#define OFF_XV 8388608u
#define OFF_WQ 12582912u
#define OFF_WK 13631488u
#define OFF_WV 14680064u
#define OFF_WO 15728640u
#define OFF_QH 16777216u
#define OFF_KH 20971520u
#define OFF_VH 25165824u
#define OFF_KC OFF_XQ
#define OFF_VT OFF_XK
#define OFF_AT OFF_VH

#if __has_builtin(__builtin_amdgcn_exp2f)
#define EXP2(x) __builtin_amdgcn_exp2f(x)
#else
static __device__ __forceinline__ float EXP2(float x) {
    float r;
    asm volatile("v_exp_f32 %0, %1" : "=v"(r) : "v"(x));
    return r;
}
#endif

__device__ __forceinline__ unsigned cvt_pk(float lo, float hi) {
    unsigned r;
    asm volatile("v_cvt_pk_bf16_f32 %0, %1, %2" : "=v"(r) : "v"(lo), "v"(hi));
    return r;
}

__device__ __forceinline__ unsigned short f2b(float f) {
    unsigned u = __builtin_bit_cast(unsigned, f);
    u += 0x7fffu + ((u >> 16) & 1u);
    return (unsigned short)(u >> 16);
}

typedef const __attribute__((address_space(1))) unsigned int* gas_t;
typedef __attribute__((address_space(3))) unsigned int* las_t;

__device__ __forceinline__ void gload_lds16(const ushort* g, ushort* l) {
    __builtin_amdgcn_global_load_lds((gas_t)(const void*)g, (las_t)(void*)l, 16, 0, 0);
}

__global__ __launch_bounds__(256)
void cvt_kernel(const float* __restrict__ q, const float* __restrict__ k,
                const float* __restrict__ v, const float* __restrict__ wq,
                const float* __restrict__ wk, const float* __restrict__ wv,
                const float* __restrict__ wo, ushort* __restrict__ ws)
{
    const float* src; unsigned n; unsigned dst;
    switch (blockIdx.y) {
        case 0: src = q;  n = 4194304u; dst = OFF_XQ; break;
        case 1: src = k;  n = 4194304u; dst = OFF_XK; break;
        case 2: src = v;  n = 4194304u; dst = OFF_XV; break;
        case 3: src = wq; n = 1048576u; dst = OFF_WQ; break;
        case 4: src = wk; n = 1048576u; dst = OFF_WK; break;
        case 5: src = wv; n = 1048576u; dst = OFF_WV; break;
        default: src = wo; n = 1048576u; dst = OFF_WO; break;
    }
    unsigned i = (blockIdx.x * 256u + threadIdx.x) * 4u;
    if (i >= n) return;
    float4 f = *(const float4*)(src + i);
    ushort4 o;
    o.x = f2b(f.x); o.y = f2b(f.y); o.z = f2b(f.z); o.w = f2b(f.w);
    *(ushort4*)(ws + dst + i) = o;
}

// C = A @ B^T, A:[4096][1024] bf16, B:[1024][1024] bf16, row-major.
// m97 structure: linear LDS, global_load_lds width-16.
template<bool PROJ>
__global__ __launch_bounds__(256)
void gemm_bt(const ushort* __restrict__ Abase, const ushort* __restrict__ Bbase,
             ushort* __restrict__ obf, float* __restrict__ of)
{
    __shared__ __align__(16) ushort lA[128 * 64];
    __shared__ __align__(16) ushort lB[128 * 64];

    const ushort* A = Abase;
    const ushort* Bw = Bbase;
    ushort* dst = obf;
    float scale = 1.0f;
    if (PROJ) {
        unsigned z = blockIdx.z;
        A  += (size_t)z * (GM * GK);
        Bw += (size_t)z * (GN * GK);
        dst += (size_t)z * (GM * GN);
        if (z == 0) scale = 0.125f * 1.44269504088896f;  // 1/sqrt(64) * log2(e)
    }

    const int tid = threadIdx.x;
    const int lane = tid & 63, wid = tid >> 6;
    const int wr = wid >> 1, wc = wid & 1;
    const int lr = lane & 15, lg = lane >> 4;
    const int m0 = blockIdx.y * 128, n0 = blockIdx.x * 128;
    const int srow = wid * 32 + (lane >> 3);
    const int scol = (lane & 7) * 8;

    f32x4 acc[4][4] = {};

    for (int k0 = 0; k0 < GK; k0 += 64) {
        __syncthreads();
#pragma unroll
        for (int p = 0; p < 4; ++p) {
            gload_lds16(A + (size_t)(m0 + srow + p * 8) * GK + k0 + scol,
                        &lA[(wid * 32 + p * 8) * 64]);
            gload_lds16(Bw + (size_t)(n0 + srow + p * 8) * GK + k0 + scol,
                        &lB[(wid * 32 + p * 8) * 64]);
        }
        __syncthreads();
#pragma unroll
        for (int kk = 0; kk < 2; ++kk) {
            bf16x8 af[4], bfr[4];
#pragma unroll
            for (int i = 0; i < 4; ++i) {
                af[i]  = *(const bf16x8*)(&lA[(wr * 64 + i * 16 + lr) * 64 + kk * 32 + lg * 8]);
                bfr[i] = *(const bf16x8*)(&lB[(wc * 64 + i * 16 + lr) * 64 + kk * 32 + lg * 8]);
            }
#pragma unroll
            for (int i = 0; i < 4; ++i)
#pragma unroll
                for (int j = 0; j < 4; ++j)
                    acc[i][j] = __builtin_amdgcn_mfma_f32_16x16x32_bf16(af[i], bfr[j], acc[i][j], 0, 0, 0);
        }
    }

#pragma unroll
    for (int i = 0; i < 4; ++i) {
#pragma unroll
        for (int j = 0; j < 4; ++j) {
            int col = n0 + wc * 64 + j * 16 + lr;
#pragma unroll
            for (int r = 0; r < 4; ++r) {
                int row = m0 + wr * 64 + i * 16 + lg * 4 + r;
                float val = acc[i][j][r] * scale;
                if (PROJ) {
                    int b = row >> 11, s = row & 2047;
                    int hh = col >> 6, dk = col & 63;
                    dst[(((size_t)b * NH + hh) * SEQ + s) * DKH + dk] = f2b(val);
                } else {
                    of[(size_t)row * GN + col] = val;
                }
            }
        }
    }
}

// Per-batch compaction index: idx[b][c] = s of c-th unmasked key; m[b] = count.
__global__ __launch_bounds__(256)
void scan_kernel(const int* __restrict__ mask, int* __restrict__ idx, int* __restrict__ mbuf)
{
    const int b = blockIdx.x;
    const int* mp = mask + (size_t)b * SEQ;
    const int tid = threadIdx.x;
    const int lane = tid & 63, w = tid >> 6;
    int v[8];
    int cnt = 0;
#pragma unroll
    for (int j = 0; j < 8; ++j) { v[j] = mp[tid * 8 + j]; cnt += (v[j] != 0); }
    int inc = cnt;
#pragma unroll
    for (int d = 1; d < 64; d <<= 1) {
        int t = __shfl_up(inc, d);
        if (lane >= d) inc += t;
    }
    __shared__ int wsum[4];
    if (lane == 63) wsum[w] = inc;
    __syncthreads();
    int base = inc - cnt;
    for (int i = 0; i < w; ++i) base += wsum[i];
    int c = base;
    int* ob = idx + (size_t)b * SEQ;
#pragma unroll
    for (int j = 0; j < 8; ++j)
        if (v[j] != 0) ob[c++] = tid * 8 + j;
    if (tid == 255) mbuf[b] = base + cnt;
}

// Gather compacted K rows; build sigma-permuted transposed V^T[d][pos].
// sigma(p) = (p&3)*16 + (p>>2) within each 64-key tile (matches P pack order).
__global__ __launch_bounds__(256)
void gather_kernel(ushort* __restrict__ ws, const int* __restrict__ idx,
                   const int* __restrict__ mbuf)
{
    const int t = blockIdx.x;
    const int bh = blockIdx.y;
    const int b = bh >> 4;
    const int mb = mbuf[b];
    if (t * 64 >= mb) return;
    const int* ix = idx + (size_t)b * SEQ;
    const ushort* Kh = ws + OFF_KH + (size_t)bh * (SEQ * DKH);
    const ushort* Vh = ws + OFF_VH + (size_t)bh * (SEQ * DKH);
    ushort* Kc = ws + OFF_KC + (size_t)bh * (SEQ * DKH);
    ushort* VT = ws + OFF_VT + (size_t)bh * (DKH * SEQ);

    __shared__ __align__(16) ushort lv[64][72];
    const int tid = threadIdx.x;

#pragma unroll
    for (int it = 0; it < 2; ++it) {
        int g = it * 256 + tid;
        int row = g >> 3, gi = g & 7;
        int ck = t * 64 + row;
        uint4 kv = {0, 0, 0, 0}, vv = {0, 0, 0, 0};
        if (ck < mb) kv = *(const uint4*)(Kh + (size_t)ix[ck] * DKH + gi * 8);
        *(uint4*)(Kc + (size_t)ck * DKH + gi * 8) = kv;
        int cv = t * 64 + ((row & 3) * 16 + (row >> 2));
        if (cv < mb) vv = *(const uint4*)(Vh + (size_t)ix[cv] * DKH + gi * 8);
        *(uint4*)(&lv[row][gi * 8]) = vv;
    }
    __syncthreads();
#pragma unroll
    for (int it = 0; it < 2; ++it) {
        int g = it * 256 + tid;
        int d = g >> 3, gp = g & 7;
        ushort tmp[8];
#pragma unroll
        for (int j = 0; j < 8; ++j) tmp[j] = lv[gp * 8 + j][d];
        *(uint4*)(VT + (size_t)d * SEQ + t * 64 + gp * 8) = *(const uint4*)tmp;
    }
}

// Flash attention over compacted keys, fixed-max softmax (Q pre-scaled 0.125*log2e).
// Block = (b, h, q-tile of 64). 4 waves x 16 q-rows. KV tile = 64 compact keys.
// Double-buffered gload_lds staging with XOR-swizzle baked via per-lane global src.
__global__ __launch_bounds__(256)
void attn_kernel(ushort* __restrict__ ws, const int* __restrict__ mbuf)
{
    const int bid = blockIdx.x;
    const int qt = bid & 31;
    const int h  = (bid >> 5) & 15;
    const int b  = bid >> 9;
    const int bh = b * NH + h;

    const ushort* Qp = ws + OFF_QH + (size_t)bh * (SEQ * DKH);
    const ushort* Kc = ws + OFF_KC + (size_t)bh * (SEQ * DKH);
    const ushort* VT = ws + OFF_VT + (size_t)bh * (DKH * SEQ);
    ushort* At = ws + OFF_AT;

    const int mb = mbuf[b];
    const int nt = (mb + 63) >> 6;

    __shared__ __align__(16) ushort lK[2][64 * 64];
    __shared__ __align__(16) ushort lV[2][64 * 64];
    __shared__ __align__(16) ushort lP[4][16][72];

    const int tid = threadIdx.x;
    const int lane = tid & 63, wid = tid >> 6;
    const int lr = lane & 15, lg = lane >> 4;
    ushort* lPw = &lP[wid][0][0];

    const int srow = wid * 16 + (lane >> 3);   // + c*8
    const int sg = lane & 7;

    const int qrow0 = qt * 64 + wid * 16;
    bf16x8 qf[2];
#pragma unroll
    for (int kk = 0; kk < 2; ++kk)
        qf[kk] = *(const bf16x8*)(Qp + (size_t)(qrow0 + lr) * DKH + kk * 32 + lg * 8);

    f32x4 acc_o[4] = {};
    float lrun[4] = {0.f, 0.f, 0.f, 0.f};

    auto STAGE = [&](int buf, int kt) {
        const int kbase = kt * 64;
#pragma unroll
        for (int c = 0; c < 2; ++c) {
            int r = srow + c * 8;
            gload_lds16(Kc + (size_t)(kbase + r) * DKH + ((sg ^ (r & 7)) * 8),
                        &lK[buf][(wid * 16 + c * 8) * 64]);
            gload_lds16(VT + (size_t)r * SEQ + kbase + ((sg ^ (r & 7)) * 8),
                        &lV[buf][(wid * 16 + c * 8) * 64]);
        }
    };

    STAGE(0, 0);
    __syncthreads();

    for (int kt = 0; kt < nt; ++kt) {
        const int cur = kt & 1;
        if (kt + 1 < nt) STAGE(cur ^ 1, kt + 1);
        const ushort* lKc = lK[cur];
        const ushort* lVc = lV[cur];

        // S = Q K^T (keys = compact fc*16+lr)
        f32x4 s[4];
#pragma unroll
        for (int fc = 0; fc < 4; ++fc) {
            int row = fc * 16 + lr;
            int sw = row & 7;
            bf16x8 kf0 = *(const bf16x8*)(lKc + row * 64 + ((lg ^ sw) * 8));
            bf16x8 kf1 = *(const bf16x8*)(lKc + row * 64 + (((4 + lg) ^ sw) * 8));
            f32x4 t = {};
            t = __builtin_amdgcn_mfma_f32_16x16x32_bf16(qf[0], kf0, t, 0, 0, 0);
            t = __builtin_amdgcn_mfma_f32_16x16x32_bf16(qf[1], kf1, t, 0, 0, 0);
            s[fc] = t;
        }

        if (kt == nt - 1) {
            const int kbase = kt * 64;
#pragma unroll
            for (int fc = 0; fc < 4; ++fc)
                if (kbase + fc * 16 + lr >= mb)
                    s[fc] = f32x4{NEGV, NEGV, NEGV, NEGV};
        }

        // softmax (fixed max): p = 2^s; pack P sigma-permuted (pos = lr*4+fc)
#pragma unroll
        for (int r = 0; r < 4; ++r) {
            float p0 = EXP2(s[0][r]), p1 = EXP2(s[1][r]);
            float p2 = EXP2(s[2][r]), p3 = EXP2(s[3][r]);
            lrun[r] += (p0 + p1) + (p2 + p3);
            uint2 pk;
            pk.x = cvt_pk(p0, p1);
            pk.y = cvt_pk(p2, p3);
            *(uint2*)(lPw + (lg * 4 + r) * 72 + lr * 4) = pk;
        }

        // O += P @ V (contraction over sigma positions)
#pragma unroll
        for (int kk = 0; kk < 2; ++kk) {
            bf16x8 pf = *(const bf16x8*)(lPw + lr * 72 + kk * 32 + lg * 8);
#pragma unroll
            for (int fc2 = 0; fc2 < 4; ++fc2) {
                int d = fc2 * 16 + lr;
                bf16x8 vf = *(const bf16x8*)(lVc + d * 64 + (((kk * 4 + lg) ^ (d & 7)) * 8));
                acc_o[fc2] = __builtin_amdgcn_mfma_f32_16x16x32_bf16(pf, vf, acc_o[fc2], 0, 0, 0);
            }
        }
        __syncthreads();
    }

    // epilogue: reduce row-sums across lr, divide, write concat bf16
#pragma unroll
    for (int r = 0; r < 4; ++r) {
        float l = lrun[r];
        l += __shfl_xor(l, 1);
        l += __shfl_xor(l, 2);
        l += __shfl_xor(l, 4);
        l += __shfl_xor(l, 8);
        float rl = 1.0f / l;
        int qrow = qrow0 + lg * 4 + r;
#pragma unroll
        for (int fc2 = 0; fc2 < 4; ++fc2)
            At[((size_t)(b * SEQ) + qrow) * DM + h * DKH + fc2 * 16 + lr] =
                f2b(acc_o[fc2][r] * rl);
    }
}

extern "C" void kernel_launch(void* const* d_in, const int* in_sizes, int n_in,
                              void* d_out, int out_size, void* d_ws, size_t ws_size,
                              hipStream_t stream) {
    const float* kin = (const float*)d_in[0];
    const float* vin = (const float*)d_in[1];
    const float* qin = (const float*)d_in[2];
    const int*   msk = (const int*)d_in[3];
    const float* wq  = (const float*)d_in[4];
    const float* wk  = (const float*)d_in[5];
    const float* wv  = (const float*)d_in[6];
    const float* wo  = (const float*)d_in[7];
    ushort* ws = (ushort*)d_ws;
    float* out = (float*)d_out;
    int* idxb = (int*)(ws + OFF_WQ);       // 16KB, dead-Wq region (post-proj)
    int* mbuf = idxb + 4096;

    cvt_kernel<<<dim3(4096, 7), 256, 0, stream>>>(qin, kin, vin, wq, wk, wv, wo, ws);
    gemm_bt<true><<<dim3(8, 32, 3), 256, 0, stream>>>(ws + OFF_XQ, ws + OFF_WQ, ws + OFF_QH, nullptr);
    scan_kernel<<<2, 256, 0, stream>>>(msk, idxb, mbuf);
    gather_kernel<<<dim3(32, 32), 256, 0, stream>>>(ws, idxb, mbuf);
    attn_kernel<<<1024, 256, 0, stream>>>(ws, mbuf);
    gemm_bt<false><<<dim3(8, 32, 1), 256, 0, stream>>>(ws + OFF_AT, ws + OFF_WO, nullptr, out);
}